// Round 3
// baseline (862.744 us; speedup 1.0000x reference)
//
#include <hip/hip_runtime.h>
#include <hip/hip_bf16.h>

// EdgeAwareCritic: 3x GATv2 (H=2 heads, HID=128) + FiLM + MLP head, scalar output.
// fp32 inputs; GEMMs run in bf16 MFMA (fp32 accumulate), GAT edge path stays fp32.

typedef __attribute__((ext_vector_type(8))) short bf16x8;   // 8 bf16 = 4 VGPR
typedef __attribute__((ext_vector_type(4))) float f32x4;

__device__ __forceinline__ unsigned short f2bf(float f) {
    union { float f; unsigned int i; } v; v.f = f;
    unsigned int x = v.i;
    x += 0x7fffu + ((x >> 16) & 1u);   // round-to-nearest-even
    return (unsigned short)(x >> 16);
}

// ---------------- multi-tensor fp32 -> bf16 convert (RNE) ----------------
#define MAXCVT 12
struct CvtDescs {
    const float* src[MAXCVT];
    unsigned short* dst[MAXCVT];
    int n4[MAXCVT];       // element count / 4
    int cnt;
};
__global__ __launch_bounds__(256) void cvt_many_kernel(CvtDescs d) {
    const int tid = blockIdx.x * blockDim.x + threadIdx.x;
    const int stride = gridDim.x * blockDim.x;
    for (int e = 0; e < d.cnt; ++e) {
        const float4* s = (const float4*)d.src[e];
        ushort4* o = (ushort4*)d.dst[e];
        const int n = d.n4[e];
        for (int i = tid; i < n; i += stride) {
            float4 v = s[i];
            o[i] = make_ushort4(f2bf(v.x), f2bf(v.y), f2bf(v.z), f2bf(v.w));
        }
    }
}

// ---------------- CSR build ----------------
__global__ void hist_kernel(const int* __restrict__ dst, int* __restrict__ deg, int n) {
    int i = blockIdx.x * blockDim.x + threadIdx.x;
    if (i < n) atomicAdd(&deg[dst[i]], 1);
}

__global__ __launch_bounds__(1024) void scan_kernel(const int* __restrict__ deg,
                                                    int* __restrict__ rowp,
                                                    int* __restrict__ cur, int n) {
    __shared__ int sums[1024];
    const int t = threadIdx.x;
    const int PER = 20;                 // 1024*20 = 20480 >= 20000
    int base = t * PER;
    int local[PER];
    int run = 0;
#pragma unroll
    for (int i = 0; i < PER; ++i) {
        int v = (base + i < n) ? deg[base + i] : 0;
        local[i] = run; run += v;
    }
    sums[t] = run; __syncthreads();
    for (int off = 1; off < 1024; off <<= 1) {
        int v = (t >= off) ? sums[t - off] : 0;
        __syncthreads();
        sums[t] += v;
        __syncthreads();
    }
    int offs = (t > 0) ? sums[t - 1] : 0;
#pragma unroll
    for (int i = 0; i < PER; ++i) {
        int idx = base + i;
        if (idx < n) { int v = offs + local[i]; rowp[idx] = v; cur[idx] = v; }
    }
    if (t == 0) rowp[n] = sums[1023];
}

__global__ void scatter_kernel(const int* __restrict__ src, const int* __restrict__ dst,
                               int* __restrict__ cur, int* __restrict__ csrs,
                               int* __restrict__ csre, int n) {
    int i = blockIdx.x * blockDim.x + threadIdx.x;
    if (i < n) {
        int d = dst[i];
        int p = atomicAdd(&cur[d], 1);
        csrs[p] = src[i];
        csre[p] = i;
    }
}

// ---------------- bf16 MFMA GEMM: C[M,N] = A[M,K]bf16 @ W[N,K]bf16^T + bias ----
// LDS-free: K=128 is tiny; fragments load straight from global (L1/L2 served).
// Block 256 thr = 4 waves in 2x2 grid -> 128x128 tile. M must be %16, N %128.
template <bool RELU, bool WF32, bool WBF16>
__global__ __launch_bounds__(256) void gemm_mfma_kernel(
    const unsigned short* __restrict__ A, const unsigned short* __restrict__ W,
    const float* __restrict__ bias, float* __restrict__ C,
    unsigned short* __restrict__ Cbf, int M, int N, int K) {
    const int t = threadIdx.x;
    const int wave = t >> 6, lane = t & 63;
    const int lo = lane & 15, quad = lane >> 4;
    const int m0 = blockIdx.y * 128 + (wave & 1) * 64;
    const int n0 = blockIdx.x * 128 + (wave >> 1) * 64;

    f32x4 acc[4][4];
#pragma unroll
    for (int i = 0; i < 4; ++i)
#pragma unroll
        for (int j = 0; j < 4; ++j) acc[i][j] = (f32x4){0.f, 0.f, 0.f, 0.f};

    for (int k0 = 0; k0 < K; k0 += 32) {
        bf16x8 af[4], bf[4];
#pragma unroll
        for (int mi = 0; mi < 4; ++mi) {
            const int mb = m0 + mi * 16;
            if (mb < M)
                af[mi] = *(const bf16x8*)(A + (size_t)(mb + lo) * K + k0 + quad * 8);
            else
                af[mi] = (bf16x8){0, 0, 0, 0, 0, 0, 0, 0};
        }
#pragma unroll
        for (int ni = 0; ni < 4; ++ni)
            bf[ni] = *(const bf16x8*)(W + (size_t)(n0 + ni * 16 + lo) * K + k0 + quad * 8);
#pragma unroll
        for (int mi = 0; mi < 4; ++mi)
#pragma unroll
            for (int ni = 0; ni < 4; ++ni)
                acc[mi][ni] = __builtin_amdgcn_mfma_f32_16x16x32_bf16(af[mi], bf[ni], acc[mi][ni], 0, 0, 0);
    }

    float bn[4];
#pragma unroll
    for (int ni = 0; ni < 4; ++ni) bn[ni] = bias[n0 + ni * 16 + lo];
#pragma unroll
    for (int mi = 0; mi < 4; ++mi) {
        const int mb = m0 + mi * 16;
        if (mb >= M) continue;
#pragma unroll
        for (int ni = 0; ni < 4; ++ni) {
            const int n = n0 + ni * 16 + lo;
#pragma unroll
            for (int r = 0; r < 4; ++r) {
                float o = acc[mi][ni][r] + bn[ni];
                if (RELU) o = fmaxf(o, 0.f);
                const size_t idx = (size_t)(mb + quad * 4 + r) * N + n;
                if (WF32) C[idx] = o;
                if (WBF16) Cbf[idx] = f2bf(o);
            }
        }
    }
}

// ---------------- fp32 vector GEMM (only for ap: K=16) ----------------
template <int BK, bool RELU, bool WBF16>
__global__ __launch_bounds__(256) void gemm_kernel(const float* __restrict__ A,
                                                   const float* __restrict__ W,
                                                   const float* __restrict__ bp,
                                                   float* __restrict__ C,
                                                   unsigned short* __restrict__ Cbf,
                                                   int M, int N, int K) {
    __shared__ float As[BK][68];
    __shared__ float Ws[BK][68];
    const int t = threadIdx.x;
    const int m0 = blockIdx.y * 64;
    const int n0 = blockIdx.x * 64;
    const int tx = t & 15, ty = t >> 4;
    float acc[4][4];
#pragma unroll
    for (int i = 0; i < 4; ++i)
#pragma unroll
        for (int j = 0; j < 4; ++j) acc[i][j] = 0.f;

    for (int k0 = 0; k0 < K; k0 += BK) {
        const int r = t >> 2, cc = (t & 3) * 4;
        const int arow = m0 + r;
        float4 av = (arow < M) ? *(const float4*)(A + (size_t)arow * K + k0 + cc)
                               : make_float4(0.f, 0.f, 0.f, 0.f);
        As[cc + 0][r] = av.x; As[cc + 1][r] = av.y;
        As[cc + 2][r] = av.z; As[cc + 3][r] = av.w;
        float4 wv = *(const float4*)(W + (size_t)(n0 + r) * K + k0 + cc);
        Ws[cc + 0][r] = wv.x; Ws[cc + 1][r] = wv.y;
        Ws[cc + 2][r] = wv.z; Ws[cc + 3][r] = wv.w;
        __syncthreads();
#pragma unroll
        for (int k = 0; k < BK; ++k) {
            float4 a4 = *(const float4*)&As[k][ty * 4];
            float4 b4 = *(const float4*)&Ws[k][tx * 4];
            float a_[4] = {a4.x, a4.y, a4.z, a4.w};
            float b_[4] = {b4.x, b4.y, b4.z, b4.w};
#pragma unroll
            for (int i = 0; i < 4; ++i)
#pragma unroll
                for (int j = 0; j < 4; ++j) acc[i][j] += a_[i] * b_[j];
        }
        __syncthreads();
    }
    float4 bj = *(const float4*)(bp + n0 + tx * 4);
    float bb[4] = {bj.x, bj.y, bj.z, bj.w};
#pragma unroll
    for (int i = 0; i < 4; ++i) {
        int row = m0 + ty * 4 + i;
        if (row < M) {
            float o[4];
#pragma unroll
            for (int j = 0; j < 4; ++j) {
                o[j] = acc[i][j] + bb[j];
                if (RELU) o[j] = fmaxf(o[j], 0.f);
            }
            *(float4*)(C + (size_t)row * N + n0 + tx * 4) = make_float4(o[0], o[1], o[2], o[3]);
            if (WBF16)
                *(ushort4*)(Cbf + (size_t)row * N + n0 + tx * 4) =
                    make_ushort4(f2bf(o[0]), f2bf(o[1]), f2bf(o[2]), f2bf(o[3]));
        }
    }
}

// ---------------- GATv2 edge kernel: one wave per dst node, online softmax, 2-edge unroll
// xl/xr: [N,256] f32 (feature idx = h*128+c). out: relu(mean_heads + bias) in f32 + bf16.
__global__ __launch_bounds__(256) void gat_kernel(
    const float* __restrict__ xl, const float* __restrict__ xr,
    const int* __restrict__ rowp, const int* __restrict__ csrs, const int* __restrict__ csre,
    const float* __restrict__ ea, const float* __restrict__ We,
    const float* __restrict__ att, const float* __restrict__ bias,
    float* __restrict__ hout, unsigned short* __restrict__ hbf, int nnodes) {
    __shared__ float WeT[16][256];   // WeT[k][f] = We[f][k]
    const int t = threadIdx.x;
    {
        const float4* wp = (const float4*)(We + t * 16);
#pragma unroll
        for (int q = 0; q < 4; ++q) {
            float4 u = wp[q];
            WeT[q * 4 + 0][t] = u.x; WeT[q * 4 + 1][t] = u.y;
            WeT[q * 4 + 2][t] = u.z; WeT[q * 4 + 3][t] = u.w;
        }
    }
    __syncthreads();
    const int l = t & 63;                       // lane owns features 4l..4l+3 (head = l>=32)
    const int node = blockIdx.x * 4 + (t >> 6);
    if (node >= nnodes) return;
    const int rs = rowp[node], re = rowp[node + 1];
    const float4 xr4 = *(const float4*)(xr + (size_t)node * 256 + 4 * l);
    const float4 att4 = *(const float4*)(att + 4 * l);
    float mrun = -INFINITY, drun = 0.f;
    float ax = 0.f, ay = 0.f, az = 0.f, aw = 0.f;
    for (int i = rs; i < re; i += 2) {
        const bool two = (i + 1 < re);
        const int s0 = csrs[i],               e0 = csre[i];
        const int s1 = two ? csrs[i + 1] : s0, e1 = two ? csre[i + 1] : e0;
        const float4 xl0 = *(const float4*)(xl + (size_t)s0 * 256 + 4 * l);
        const float4 xl1 = *(const float4*)(xl + (size_t)s1 * 256 + 4 * l);
        const float4* ep0 = (const float4*)(ea + (size_t)e0 * 16);
        const float4* ep1 = (const float4*)(ea + (size_t)e1 * 16);
        float ev0[16], ev1[16];
#pragma unroll
        for (int q = 0; q < 4; ++q) {
            float4 u0 = ep0[q], u1 = ep1[q];
            ev0[q * 4 + 0] = u0.x; ev0[q * 4 + 1] = u0.y; ev0[q * 4 + 2] = u0.z; ev0[q * 4 + 3] = u0.w;
            ev1[q * 4 + 0] = u1.x; ev1[q * 4 + 1] = u1.y; ev1[q * 4 + 2] = u1.z; ev1[q * 4 + 3] = u1.w;
        }
        float e0x = 0.f, e0y = 0.f, e0z = 0.f, e0w = 0.f;
        float e1x = 0.f, e1y = 0.f, e1z = 0.f, e1w = 0.f;
#pragma unroll
        for (int k = 0; k < 16; ++k) {
            float4 wv = *(const float4*)&WeT[k][4 * l];
            e0x += ev0[k] * wv.x; e0y += ev0[k] * wv.y; e0z += ev0[k] * wv.z; e0w += ev0[k] * wv.w;
            e1x += ev1[k] * wv.x; e1y += ev1[k] * wv.y; e1z += ev1[k] * wv.z; e1w += ev1[k] * wv.w;
        }
        float s0x = xl0.x + xr4.x + e0x, s0y = xl0.y + xr4.y + e0y;
        float s0z = xl0.z + xr4.z + e0z, s0w = xl0.w + xr4.w + e0w;
        float s1x = xl1.x + xr4.x + e1x, s1y = xl1.y + xr4.y + e1y;
        float s1z = xl1.z + xr4.z + e1z, s1w = xl1.w + xr4.w + e1w;
        s0x = s0x > 0.f ? s0x : 0.2f * s0x;  s0y = s0y > 0.f ? s0y : 0.2f * s0y;
        s0z = s0z > 0.f ? s0z : 0.2f * s0z;  s0w = s0w > 0.f ? s0w : 0.2f * s0w;
        s1x = s1x > 0.f ? s1x : 0.2f * s1x;  s1y = s1y > 0.f ? s1y : 0.2f * s1y;
        s1z = s1z > 0.f ? s1z : 0.2f * s1z;  s1w = s1w > 0.f ? s1w : 0.2f * s1w;
        float t0 = s0x * att4.x + s0y * att4.y + s0z * att4.z + s0w * att4.w;
        float t1 = s1x * att4.x + s1y * att4.y + s1z * att4.z + s1w * att4.w;
        // per-head reduce (offsets stay inside each 32-lane half); two chains interleaved
        t0 += __shfl_xor(t0, 1);  t1 += __shfl_xor(t1, 1);
        t0 += __shfl_xor(t0, 2);  t1 += __shfl_xor(t1, 2);
        t0 += __shfl_xor(t0, 4);  t1 += __shfl_xor(t1, 4);
        t0 += __shfl_xor(t0, 8);  t1 += __shfl_xor(t1, 8);
        t0 += __shfl_xor(t0, 16); t1 += __shfl_xor(t1, 16);
        // when !two: s1==s0 so t1==t0 -> nm unaffected; p1 forced to 0
        float nm = fmaxf(mrun, fmaxf(t0, t1));
        float p0 = __expf(t0 - nm);
        float p1 = two ? __expf(t1 - nm) : 0.f;
        float sc = __expf(mrun - nm);    // first pair: exp(-inf)=0
        drun = drun * sc + p0 + p1;
        ax = ax * sc + p0 * xl0.x + p1 * xl1.x;
        ay = ay * sc + p0 * xl0.y + p1 * xl1.y;
        az = az * sc + p0 * xl0.z + p1 * xl1.z;
        aw = aw * sc + p0 * xl0.w + p1 * xl1.w;
        mrun = nm;
    }
    float ox, oy, oz, ow;
    if (re > rs) {
        float inv = 1.f / drun;
        ox = ax * inv; oy = ay * inv; oz = az * inv; ow = aw * inv;
    } else { ox = oy = oz = ow = 0.f; }   // isolated node: segment_sum over empty = 0
    // mean over heads: lane l (head0) pairs with lane l^32 (head1, same channels)
    ox += __shfl_xor(ox, 32); oy += __shfl_xor(oy, 32);
    oz += __shfl_xor(oz, 32); ow += __shfl_xor(ow, 32);
    if (l < 32) {
        float4 bu = *(const float4*)(bias + 4 * l);
        float4 o;
        o.x = fmaxf(0.5f * ox + bu.x, 0.f);
        o.y = fmaxf(0.5f * oy + bu.y, 0.f);
        o.z = fmaxf(0.5f * oz + bu.z, 0.f);
        o.w = fmaxf(0.5f * ow + bu.w, 0.f);
        *(float4*)(hout + (size_t)node * 128 + 4 * l) = o;
        *(ushort4*)(hbf + (size_t)node * 128 + 4 * l) =
            make_ushort4(f2bf(o.x), f2bf(o.y), f2bf(o.z), f2bf(o.w));
    }
}

// ---------------- FiLM: hbf = bf16(gm*h + bm) ----------------
__global__ void film_kernel(const float4* __restrict__ h, const float4* __restrict__ gm,
                            const float4* __restrict__ bm, ushort4* __restrict__ hbf, int n4) {
    for (int i = blockIdx.x * blockDim.x + threadIdx.x; i < n4; i += gridDim.x * blockDim.x) {
        float4 hv = h[i], g = gm[i], b = bm[i];
        float ox = g.x * hv.x + b.x, oy = g.y * hv.y + b.y;
        float oz = g.z * hv.z + b.z, ow = g.w * hv.w + b.w;
        hbf[i] = make_ushort4(f2bf(ox), f2bf(oy), f2bf(oz), f2bf(ow));
    }
}

// ---------------- column sum of h[rows,128] -> col[128] ----------------
__global__ __launch_bounds__(256) void colsum_kernel(const float* __restrict__ h,
                                                     float* __restrict__ col, int rows) {
    int c = threadIdx.x & 127;
    int r = blockIdx.x * 2 + (threadIdx.x >> 7);
    float s = 0.f;
    for (; r < rows; r += gridDim.x * 2) s += h[(size_t)r * 128 + c];
    atomicAdd(&col[c], s);
}

// ---------------- out = dot(col/N, q2_W) + q2_b ----------------
__global__ __launch_bounds__(128) void final_kernel(const float* __restrict__ col,
                                                    const float* __restrict__ q2w,
                                                    const float* __restrict__ q2b,
                                                    float* __restrict__ out, float invn) {
    __shared__ float red[128];
    int t = threadIdx.x;
    red[t] = col[t] * invn * q2w[t];
    __syncthreads();
    for (int off = 64; off > 0; off >>= 1) {
        if (t < off) red[t] += red[t + off];
        __syncthreads();
    }
    if (t == 0) out[0] = red[0] + q2b[0];
}

extern "C" void kernel_launch(void* const* d_in, const int* in_sizes, int n_in,
                              void* d_out, int out_size, void* d_ws, size_t ws_size,
                              hipStream_t stream) {
    const int N = in_sizes[0] / 128;   // 20000
    const int E = in_sizes[1] / 2;     // 320000

    typedef const float* fp;
    fp x      = (fp)d_in[0];
    const int* ei = (const int*)d_in[1];
    fp ea     = (fp)d_in[2];
    fp action = (fp)d_in[3];
    fp inp_W  = (fp)d_in[4];
    fp inp_b  = (fp)d_in[5];
    // GAT layers: s1 @6, s2 @13, sa @20 — [Wl, bl, Wr, br, We, att, bias]
    fp ap_W = (fp)d_in[27], ap_b = (fp)d_in[28];
    fp g_W  = (fp)d_in[29], g_b  = (fp)d_in[30];
    fp be_W = (fp)d_in[31], be_b = (fp)d_in[32];
    fp q1_W = (fp)d_in[33], q1_b = (fp)d_in[34];
    fp q2_W = (fp)d_in[35], q2_b = (fp)d_in[36];

    // workspace layout (256B aligned)
    char* base = (char*)d_ws;
    size_t off = 0;
    auto alloc = [&](size_t bytes) { char* p = base + off; off = (off + bytes + 255) & ~(size_t)255; return p; };
    float* h    = (float*)alloc((size_t)N * 128 * 4);
    float* xlb  = (float*)alloc((size_t)N * 256 * 4);
    float* xrb  = (float*)alloc((size_t)N * 256 * 4);
    float* col  = (float*)alloc(128 * 4);
    int* deg    = (int*)alloc((size_t)N * 4);
    int* rowp   = (int*)alloc((size_t)(N + 1) * 4);
    int* cur    = (int*)alloc((size_t)N * 4);
    int* csrs   = (int*)alloc((size_t)E * 4);
    int* csre   = (int*)alloc((size_t)E * 4);
    unsigned short* hbf  = (unsigned short*)alloc((size_t)N * 128 * 2);
    unsigned short* xbf  = (unsigned short*)alloc((size_t)N * 128 * 2);   // reused as a_bf later
    unsigned short* wbf  = (unsigned short*)alloc(262144 * 2);            // bf16 weight pool
    float* abuf = xrb + (size_t)N * 128;   // f32 side of ap output (unused downstream)
    unsigned short* abf = xbf;             // alias: x_bf dead after inp gemm
    (void)ws_size; (void)n_in; (void)out_size;

    // bf16 weight pool offsets
    unsigned short* winp = wbf;            // 128x128
    unsigned short* w1l  = wbf + 16384;    // 256x128
    unsigned short* w1r  = w1l + 32768;
    unsigned short* w2l  = w1r + 32768;
    unsigned short* w2r  = w2l + 32768;
    unsigned short* wal  = w2r + 32768;
    unsigned short* war  = wal + 32768;
    unsigned short* wg   = war + 32768;    // 128x128
    unsigned short* wbe  = wg + 16384;
    unsigned short* wq1  = wbe + 16384;

    const int* src = ei;
    const int* dst = ei + E;

    // ---- convert x + all MFMA-consumed weights to bf16 (one launch) ----
    CvtDescs cd;
    int ce = 0;
    auto addc = [&](const float* s, unsigned short* d, int n) { cd.src[ce] = s; cd.dst[ce] = d; cd.n4[ce] = n / 4; ++ce; };
    addc(x, xbf, N * 128);
    addc(inp_W, winp, 16384);
    addc((fp)d_in[6],  w1l, 32768); addc((fp)d_in[8],  w1r, 32768);
    addc((fp)d_in[13], w2l, 32768); addc((fp)d_in[15], w2r, 32768);
    addc((fp)d_in[20], wal, 32768); addc((fp)d_in[22], war, 32768);
    addc(g_W, wg, 16384); addc(be_W, wbe, 16384); addc(q1_W, wq1, 16384);
    cd.cnt = ce;
    cvt_many_kernel<<<2048, 256, 0, stream>>>(cd);

    // ---- CSR build (reused by all 3 GAT layers) ----
    hipMemsetAsync(deg, 0, (size_t)N * 4, stream);
    hist_kernel<<<(E + 255) / 256, 256, 0, stream>>>(dst, deg, E);
    scan_kernel<<<1, 1024, 0, stream>>>(deg, rowp, cur, N);
    scatter_kernel<<<(E + 255) / 256, 256, 0, stream>>>(src, dst, cur, csrs, csre, E);

    const dim3 gm128(1, (N + 127) / 128);   // N_out=128
    const dim3 gm256(2, (N + 127) / 128);   // N_out=256

    // h0 = relu(x @ inp_W^T + inp_b) -> bf16 only (feeds s1 gemms)
    gemm_mfma_kernel<true, false, true><<<gm128, 256, 0, stream>>>(xbf, winp, inp_b, h, hbf, N, 128, 128);

    // s1
    gemm_mfma_kernel<false, true, false><<<gm256, 256, 0, stream>>>(hbf, w1l, (fp)d_in[7],  xlb, nullptr, N, 256, 128);
    gemm_mfma_kernel<false, true, false><<<gm256, 256, 0, stream>>>(hbf, w1r, (fp)d_in[9],  xrb, nullptr, N, 256, 128);
    gat_kernel<<<(N + 3) / 4, 256, 0, stream>>>(xlb, xrb, rowp, csrs, csre, ea,
                                                (fp)d_in[10], (fp)d_in[11], (fp)d_in[12], h, hbf, N);
    // s2 (gat writes h f32 for FiLM + hbf for sa gemms)
    gemm_mfma_kernel<false, true, false><<<gm256, 256, 0, stream>>>(hbf, w2l, (fp)d_in[14], xlb, nullptr, N, 256, 128);
    gemm_mfma_kernel<false, true, false><<<gm256, 256, 0, stream>>>(hbf, w2r, (fp)d_in[16], xrb, nullptr, N, 256, 128);
    gat_kernel<<<(N + 3) / 4, 256, 0, stream>>>(xlb, xrb, rowp, csrs, csre, ea,
                                                (fp)d_in[17], (fp)d_in[18], (fp)d_in[19], h, hbf, N);

    // FiLM: a = relu(action@ap^T+ap_b) [fp32 vector gemm, K=16] -> a_bf
    gemm_kernel<16, true, true><<<dim3(2, (N + 63) / 64), 256, 0, stream>>>(action, ap_W, ap_b, abuf, abf, N, 128, 16);
    gemm_mfma_kernel<false, true, false><<<gm128, 256, 0, stream>>>(abf, wg,  g_b,  xlb, nullptr, N, 128, 128);
    gemm_mfma_kernel<false, true, false><<<gm128, 256, 0, stream>>>(abf, wbe, be_b, xlb + (size_t)N * 128, nullptr, N, 128, 128);
    film_kernel<<<1024, 256, 0, stream>>>((const float4*)h, (const float4*)xlb,
                                          (const float4*)(xlb + (size_t)N * 128), (ushort4*)hbf, N * 128 / 4);

    // sa
    gemm_mfma_kernel<false, true, false><<<gm256, 256, 0, stream>>>(hbf, wal, (fp)d_in[21], xlb, nullptr, N, 256, 128);
    gemm_mfma_kernel<false, true, false><<<gm256, 256, 0, stream>>>(hbf, war, (fp)d_in[23], xrb, nullptr, N, 256, 128);
    gat_kernel<<<(N + 3) / 4, 256, 0, stream>>>(xlb, xrb, rowp, csrs, csre, ea,
                                                (fp)d_in[24], (fp)d_in[25], (fp)d_in[26], h, hbf, N);

    // q1 + scalar head: mean_n(relu(h@q1^T+b) @ q2^T + q2_b) via column-sum trick
    gemm_mfma_kernel<true, true, false><<<gm128, 256, 0, stream>>>(hbf, wq1, q1_b, xlb, nullptr, N, 128, 128);
    hipMemsetAsync(col, 0, 128 * 4, stream);
    colsum_kernel<<<256, 256, 0, stream>>>(xlb, col, N);
    final_kernel<<<1, 128, 0, stream>>>(col, q2_W, q2_b, (float*)d_out, 1.0f / (float)N);
}

// Round 4
// 841.700 us; speedup vs baseline: 1.0250x; 1.0250x over previous
//
#include <hip/hip_runtime.h>
#include <hip/hip_bf16.h>

// EdgeAwareCritic: 3x GATv2 (H=2 heads, HID=128) + FiLM + MLP head, scalar output.
// fp32 inputs; GEMMs in bf16 MFMA (fp32 accumulate); GAT edge math fp32 with
// bf16 xl/xr gathers and register-cached We (no LDS traffic in the edge loop).

typedef __attribute__((ext_vector_type(8))) short bf16x8;   // 8 bf16 = 4 VGPR
typedef __attribute__((ext_vector_type(4))) float f32x4;

__device__ __forceinline__ unsigned short f2bf(float f) {
    union { float f; unsigned int i; } v; v.f = f;
    unsigned int x = v.i;
    x += 0x7fffu + ((x >> 16) & 1u);   // round-to-nearest-even
    return (unsigned short)(x >> 16);
}
__device__ __forceinline__ float4 b4f(ushort4 u) {
    union { unsigned int i; float f; } a, b, c, d;
    a.i = (unsigned int)u.x << 16; b.i = (unsigned int)u.y << 16;
    c.i = (unsigned int)u.z << 16; d.i = (unsigned int)u.w << 16;
    return make_float4(a.f, b.f, c.f, d.f);
}

// ---------------- multi-tensor fp32 -> bf16 convert (RNE) ----------------
#define MAXCVT 12
struct CvtDescs {
    const float* src[MAXCVT];
    unsigned short* dst[MAXCVT];
    int n4[MAXCVT];
    int cnt;
};
__global__ __launch_bounds__(256) void cvt_many_kernel(CvtDescs d) {
    const int tid = blockIdx.x * blockDim.x + threadIdx.x;
    const int stride = gridDim.x * blockDim.x;
    for (int e = 0; e < d.cnt; ++e) {
        const float4* s = (const float4*)d.src[e];
        ushort4* o = (ushort4*)d.dst[e];
        const int n = d.n4[e];
        for (int i = tid; i < n; i += stride) {
            float4 v = s[i];
            o[i] = make_ushort4(f2bf(v.x), f2bf(v.y), f2bf(v.z), f2bf(v.w));
        }
    }
}

// ---------------- CSR build ----------------
__global__ void hist_kernel(const int* __restrict__ dst, int* __restrict__ deg, int n) {
    int i = blockIdx.x * blockDim.x + threadIdx.x;
    if (i < n) atomicAdd(&deg[dst[i]], 1);
}

__global__ __launch_bounds__(1024) void scan_kernel(const int* __restrict__ deg,
                                                    int* __restrict__ rowp,
                                                    int* __restrict__ cur, int n) {
    __shared__ int sums[1024];
    const int t = threadIdx.x;
    const int PER = 20;
    int base = t * PER;
    int local[PER];
    int run = 0;
#pragma unroll
    for (int i = 0; i < PER; ++i) {
        int v = (base + i < n) ? deg[base + i] : 0;
        local[i] = run; run += v;
    }
    sums[t] = run; __syncthreads();
    for (int off = 1; off < 1024; off <<= 1) {
        int v = (t >= off) ? sums[t - off] : 0;
        __syncthreads();
        sums[t] += v;
        __syncthreads();
    }
    int offs = (t > 0) ? sums[t - 1] : 0;
#pragma unroll
    for (int i = 0; i < PER; ++i) {
        int idx = base + i;
        if (idx < n) { int v = offs + local[i]; rowp[idx] = v; cur[idx] = v; }
    }
    if (t == 0) rowp[n] = sums[1023];
}

__global__ void scatter_kernel(const int* __restrict__ src, const int* __restrict__ dst,
                               int* __restrict__ cur, int* __restrict__ csrs,
                               int* __restrict__ csre, int n) {
    int i = blockIdx.x * blockDim.x + threadIdx.x;
    if (i < n) {
        int d = dst[i];
        int p = atomicAdd(&cur[d], 1);
        csrs[p] = src[i];
        csre[p] = i;
    }
}

// ---------------- bf16 MFMA GEMM: C[M,N] = A[M,K]bf16 @ W[N,K]bf16^T + bias ----
// LDS-free; block = 4 waves stacked in M (tile 128M x 64N), wave = 32M x 64N.
// Split bias: col n takes bias0[n] if n<bsplit else bias1[n-bsplit].
template <bool RELU, bool WF32, bool WBF16>
__global__ __launch_bounds__(256) void gemm_mfma_kernel(
    const unsigned short* __restrict__ A, const unsigned short* __restrict__ W,
    const float* __restrict__ bias0, const float* __restrict__ bias1, int bsplit,
    float* __restrict__ C, unsigned short* __restrict__ Cbf, int M, int N, int K) {
    const int t = threadIdx.x;
    const int wave = t >> 6, lane = t & 63;
    const int lo = lane & 15, quad = lane >> 4;
    const int m0 = blockIdx.y * 128 + wave * 32;
    const int n0 = blockIdx.x * 64;

    f32x4 acc[2][4];
#pragma unroll
    for (int i = 0; i < 2; ++i)
#pragma unroll
        for (int j = 0; j < 4; ++j) acc[i][j] = (f32x4){0.f, 0.f, 0.f, 0.f};

    for (int k0 = 0; k0 < K; k0 += 32) {
        bf16x8 af[2], bfr[4];
#pragma unroll
        for (int mi = 0; mi < 2; ++mi) {
            const int mb = m0 + mi * 16;
            if (mb < M)
                af[mi] = *(const bf16x8*)(A + (size_t)(mb + lo) * K + k0 + quad * 8);
            else
                af[mi] = (bf16x8){0, 0, 0, 0, 0, 0, 0, 0};
        }
#pragma unroll
        for (int ni = 0; ni < 4; ++ni)
            bfr[ni] = *(const bf16x8*)(W + (size_t)(n0 + ni * 16 + lo) * K + k0 + quad * 8);
#pragma unroll
        for (int mi = 0; mi < 2; ++mi)
#pragma unroll
            for (int ni = 0; ni < 4; ++ni)
                acc[mi][ni] = __builtin_amdgcn_mfma_f32_16x16x32_bf16(af[mi], bfr[ni], acc[mi][ni], 0, 0, 0);
    }

    float bn[4];
#pragma unroll
    for (int ni = 0; ni < 4; ++ni) {
        const int n = n0 + ni * 16 + lo;
        const float* bp = (n < bsplit) ? bias0 : bias1;
        const int bi = (n < bsplit) ? n : n - bsplit;
        bn[ni] = bp[bi];
    }
#pragma unroll
    for (int mi = 0; mi < 2; ++mi) {
        const int mb = m0 + mi * 16;
        if (mb >= M) continue;
#pragma unroll
        for (int ni = 0; ni < 4; ++ni) {
            const int n = n0 + ni * 16 + lo;
#pragma unroll
            for (int r = 0; r < 4; ++r) {
                float o = acc[mi][ni][r] + bn[ni];
                if (RELU) o = fmaxf(o, 0.f);
                const size_t idx = (size_t)(mb + quad * 4 + r) * N + n;
                if (WF32) C[idx] = o;
                if (WBF16) Cbf[idx] = f2bf(o);
            }
        }
    }
}

// ---------------- fp32 vector GEMM (only for ap: K=16) ----------------
template <int BK, bool RELU, bool WBF16>
__global__ __launch_bounds__(256) void gemm_kernel(const float* __restrict__ A,
                                                   const float* __restrict__ W,
                                                   const float* __restrict__ bp,
                                                   float* __restrict__ C,
                                                   unsigned short* __restrict__ Cbf,
                                                   int M, int N, int K) {
    __shared__ float As[BK][68];
    __shared__ float Ws[BK][68];
    const int t = threadIdx.x;
    const int m0 = blockIdx.y * 64;
    const int n0 = blockIdx.x * 64;
    const int tx = t & 15, ty = t >> 4;
    float acc[4][4];
#pragma unroll
    for (int i = 0; i < 4; ++i)
#pragma unroll
        for (int j = 0; j < 4; ++j) acc[i][j] = 0.f;

    for (int k0 = 0; k0 < K; k0 += BK) {
        const int r = t >> 2, cc = (t & 3) * 4;
        const int arow = m0 + r;
        float4 av = (arow < M) ? *(const float4*)(A + (size_t)arow * K + k0 + cc)
                               : make_float4(0.f, 0.f, 0.f, 0.f);
        As[cc + 0][r] = av.x; As[cc + 1][r] = av.y;
        As[cc + 2][r] = av.z; As[cc + 3][r] = av.w;
        float4 wv = *(const float4*)(W + (size_t)(n0 + r) * K + k0 + cc);
        Ws[cc + 0][r] = wv.x; Ws[cc + 1][r] = wv.y;
        Ws[cc + 2][r] = wv.z; Ws[cc + 3][r] = wv.w;
        __syncthreads();
#pragma unroll
        for (int k = 0; k < BK; ++k) {
            float4 a4 = *(const float4*)&As[k][ty * 4];
            float4 b4 = *(const float4*)&Ws[k][tx * 4];
            float a_[4] = {a4.x, a4.y, a4.z, a4.w};
            float b_[4] = {b4.x, b4.y, b4.z, b4.w};
#pragma unroll
            for (int i = 0; i < 4; ++i)
#pragma unroll
                for (int j = 0; j < 4; ++j) acc[i][j] += a_[i] * b_[j];
        }
        __syncthreads();
    }
    float4 bj = *(const float4*)(bp + n0 + tx * 4);
    float bb[4] = {bj.x, bj.y, bj.z, bj.w};
#pragma unroll
    for (int i = 0; i < 4; ++i) {
        int row = m0 + ty * 4 + i;
        if (row < M) {
            float o[4];
#pragma unroll
            for (int j = 0; j < 4; ++j) {
                o[j] = acc[i][j] + bb[j];
                if (RELU) o[j] = fmaxf(o[j], 0.f);
            }
            *(float4*)(C + (size_t)row * N + n0 + tx * 4) = make_float4(o[0], o[1], o[2], o[3]);
            if (WBF16)
                *(ushort4*)(Cbf + (size_t)row * N + n0 + tx * 4) =
                    make_ushort4(f2bf(o[0]), f2bf(o[1]), f2bf(o[2]), f2bf(o[3]));
        }
    }
}

// ---------------- GATv2 edge kernel ----------------
// 2 waves cooperate per dst node (even/odd edges), online softmax, LDS merge.
// We register-cached (64 VGPR/lane): zero LDS traffic in the edge loop.
// xfull: [N,512] bf16, cols 0-255 = xl, 256-511 = xr (feature idx = h*128+c).
__global__ __launch_bounds__(256) void gat_kernel(
    const unsigned short* __restrict__ xfull,
    const int* __restrict__ rowp, const int* __restrict__ csrs, const int* __restrict__ csre,
    const float* __restrict__ ea, const float* __restrict__ We,
    const float* __restrict__ att, const float* __restrict__ bias,
    float* __restrict__ houtf, unsigned short* __restrict__ houtb, int nnodes) {
    __shared__ float part[2][64][6];
    const int t = threadIdx.x;
    const int wave = t >> 6, lane = t & 63;
    const int sub = wave & 1, nloc = wave >> 1;
    const int node = blockIdx.x * 2 + nloc;
    const int nodeC = node < nnodes ? node : nnodes - 1;

    // register-cache We rows 4*lane .. 4*lane+3 (16 k each): wreg[j][k] = We[4l+j][k]
    float wreg[4][16];
#pragma unroll
    for (int j = 0; j < 4; ++j) {
        const float4* wp = (const float4*)(We + (size_t)(4 * lane + j) * 16);
#pragma unroll
        for (int q = 0; q < 4; ++q) {
            float4 u = wp[q];
            wreg[j][q * 4 + 0] = u.x; wreg[j][q * 4 + 1] = u.y;
            wreg[j][q * 4 + 2] = u.z; wreg[j][q * 4 + 3] = u.w;
        }
    }
    const int rs = rowp[nodeC], re = rowp[nodeC + 1];
    const float4 xr4 = b4f(*(const ushort4*)(xfull + (size_t)nodeC * 512 + 256 + 4 * lane));
    const float4 att4 = *(const float4*)(att + 4 * lane);

    float mrun = -INFINITY, drun = 0.f;
    float ax = 0.f, ay = 0.f, az = 0.f, aw = 0.f;
    int i = rs + sub;
    int sN = 0, eN = 0;
    if (i < re) { sN = csrs[i]; eN = csre[i]; }   // index prefetch (1 ahead)
    while (i < re) {
        const int s = sN, e = eN;
        const int i2 = i + 2;
        if (i2 < re) { sN = csrs[i2]; eN = csre[i2]; }
        const float4 xl4 = b4f(*(const ushort4*)(xfull + (size_t)s * 512 + 4 * lane));
        const float4* ep = (const float4*)(ea + (size_t)e * 16);
        float ev[16];
#pragma unroll
        for (int q = 0; q < 4; ++q) {
            float4 u = ep[q];
            ev[q * 4 + 0] = u.x; ev[q * 4 + 1] = u.y;
            ev[q * 4 + 2] = u.z; ev[q * 4 + 3] = u.w;
        }
        float e0 = 0.f, e1 = 0.f, e2 = 0.f, e3 = 0.f;
#pragma unroll
        for (int k = 0; k < 16; ++k) {
            e0 += ev[k] * wreg[0][k]; e1 += ev[k] * wreg[1][k];
            e2 += ev[k] * wreg[2][k]; e3 += ev[k] * wreg[3][k];
        }
        float sx = xl4.x + xr4.x + e0, sy = xl4.y + xr4.y + e1;
        float sz = xl4.z + xr4.z + e2, sw = xl4.w + xr4.w + e3;
        sx = sx > 0.f ? sx : 0.2f * sx;  sy = sy > 0.f ? sy : 0.2f * sy;
        sz = sz > 0.f ? sz : 0.2f * sz;  sw = sw > 0.f ? sw : 0.2f * sw;
        float tv = sx * att4.x + sy * att4.y + sz * att4.z + sw * att4.w;
        tv += __shfl_xor(tv, 1);  tv += __shfl_xor(tv, 2);  tv += __shfl_xor(tv, 4);
        tv += __shfl_xor(tv, 8);  tv += __shfl_xor(tv, 16);
        float nm = fmaxf(mrun, tv);
        float p  = __expf(tv - nm);
        float sc = __expf(mrun - nm);    // first edge: exp(-inf)=0
        drun = drun * sc + p;
        ax = ax * sc + p * xl4.x; ay = ay * sc + p * xl4.y;
        az = az * sc + p * xl4.z; aw = aw * sc + p * xl4.w;
        mrun = nm;
        i = i2;
    }
    // publish odd-wave partials, merge in even wave
    if (sub == 1) {
        part[nloc][lane][0] = mrun; part[nloc][lane][1] = drun;
        part[nloc][lane][2] = ax;   part[nloc][lane][3] = ay;
        part[nloc][lane][4] = az;   part[nloc][lane][5] = aw;
    }
    __syncthreads();
    if (sub == 0) {
        const float m1 = part[nloc][lane][0], d1 = part[nloc][lane][1];
        const float bx = part[nloc][lane][2], by = part[nloc][lane][3];
        const float bz = part[nloc][lane][4], bw = part[nloc][lane][5];
        float ox, oy, oz, ow;
        if (re > rs) {
            const float nm = fmaxf(mrun, m1);
            const float s0 = __expf(mrun - nm), s1 = __expf(m1 - nm);
            const float inv = 1.f / (drun * s0 + d1 * s1);
            ox = (ax * s0 + bx * s1) * inv; oy = (ay * s0 + by * s1) * inv;
            oz = (az * s0 + bz * s1) * inv; ow = (aw * s0 + bw * s1) * inv;
        } else { ox = oy = oz = ow = 0.f; }   // isolated node
        // mean over heads: lane l (head0) pairs with lane l^32 (head1, same channels)
        ox += __shfl_xor(ox, 32); oy += __shfl_xor(oy, 32);
        oz += __shfl_xor(oz, 32); ow += __shfl_xor(ow, 32);
        if (lane < 32 && node < nnodes) {
            float4 bu = *(const float4*)(bias + 4 * lane);
            float4 o;
            o.x = fmaxf(0.5f * ox + bu.x, 0.f);
            o.y = fmaxf(0.5f * oy + bu.y, 0.f);
            o.z = fmaxf(0.5f * oz + bu.z, 0.f);
            o.w = fmaxf(0.5f * ow + bu.w, 0.f);
            if (houtf) *(float4*)(houtf + (size_t)node * 128 + 4 * lane) = o;
            if (houtb) *(ushort4*)(houtb + (size_t)node * 128 + 4 * lane) =
                make_ushort4(f2bf(o.x), f2bf(o.y), f2bf(o.z), f2bf(o.w));
        }
    }
}

// ---------------- FiLM: hbf = bf16(gm*h + bm); gm|bm fused in xgb [N,256] ----
__global__ void film_kernel(const float4* __restrict__ h, const float4* __restrict__ xgb,
                            ushort4* __restrict__ hbf, int n4) {
    for (int i = blockIdx.x * blockDim.x + threadIdx.x; i < n4; i += gridDim.x * blockDim.x) {
        const int row = i >> 5, c4 = i & 31;
        float4 hv = h[i];
        float4 g = xgb[row * 64 + c4];
        float4 b = xgb[row * 64 + 32 + c4];
        float ox = g.x * hv.x + b.x, oy = g.y * hv.y + b.y;
        float oz = g.z * hv.z + b.z, ow = g.w * hv.w + b.w;
        hbf[i] = make_ushort4(f2bf(ox), f2bf(oy), f2bf(oz), f2bf(ow));
    }
}

// ---------------- column sum of h[rows,128] -> col[128] ----------------
__global__ __launch_bounds__(256) void colsum_kernel(const float* __restrict__ h,
                                                     float* __restrict__ col, int rows) {
    int c = threadIdx.x & 127;
    int r = blockIdx.x * 2 + (threadIdx.x >> 7);
    float s = 0.f;
    for (; r < rows; r += gridDim.x * 2) s += h[(size_t)r * 128 + c];
    atomicAdd(&col[c], s);
}

// ---------------- out = dot(col/N, q2_W) + q2_b ----------------
__global__ __launch_bounds__(128) void final_kernel(const float* __restrict__ col,
                                                    const float* __restrict__ q2w,
                                                    const float* __restrict__ q2b,
                                                    float* __restrict__ out, float invn) {
    __shared__ float red[128];
    int t = threadIdx.x;
    red[t] = col[t] * invn * q2w[t];
    __syncthreads();
    for (int off = 64; off > 0; off >>= 1) {
        if (t < off) red[t] += red[t + off];
        __syncthreads();
    }
    if (t == 0) out[0] = red[0] + q2b[0];
}

extern "C" void kernel_launch(void* const* d_in, const int* in_sizes, int n_in,
                              void* d_out, int out_size, void* d_ws, size_t ws_size,
                              hipStream_t stream) {
    const int N = in_sizes[0] / 128;   // 20000
    const int E = in_sizes[1] / 2;     // 320000

    typedef const float* fp;
    fp x      = (fp)d_in[0];
    const int* ei = (const int*)d_in[1];
    fp ea     = (fp)d_in[2];
    fp action = (fp)d_in[3];
    fp inp_W  = (fp)d_in[4];
    fp inp_b  = (fp)d_in[5];
    fp ap_W = (fp)d_in[27], ap_b = (fp)d_in[28];
    fp g_W  = (fp)d_in[29], g_b  = (fp)d_in[30];
    fp be_W = (fp)d_in[31], be_b = (fp)d_in[32];
    fp q1_W = (fp)d_in[33], q1_b = (fp)d_in[34];
    fp q2_W = (fp)d_in[35], q2_b = (fp)d_in[36];

    char* base = (char*)d_ws;
    size_t off = 0;
    auto alloc = [&](size_t bytes) { char* p = base + off; off = (off + bytes + 255) & ~(size_t)255; return p; };
    float* h    = (float*)alloc((size_t)N * 128 * 4);             // f32 gat out (film input)
    unsigned short* xfb = (unsigned short*)alloc((size_t)N * 512 * 2);  // fused xl|xr bf16
    float* xgb  = (float*)alloc((size_t)N * 256 * 4);             // fused gamma|beta f32 / q1 out
    float* col  = (float*)alloc(128 * 4);
    int* deg    = (int*)alloc((size_t)N * 4);
    int* rowp   = (int*)alloc((size_t)(N + 1) * 4);
    int* cur    = (int*)alloc((size_t)N * 4);
    int* csrs   = (int*)alloc((size_t)E * 4);
    int* csre   = (int*)alloc((size_t)E * 4);
    unsigned short* hbf = (unsigned short*)alloc((size_t)N * 128 * 2);
    unsigned short* xbf = (unsigned short*)alloc((size_t)N * 128 * 2);  // x bf16, later a bf16
    unsigned short* wbf = (unsigned short*)alloc(262144 * 2);
    float* abuf = (float*)xfb;             // ap f32 out: xfb region is dead at FiLM stage
    unsigned short* abf = xbf;             // x_bf dead after inp gemm
    (void)ws_size; (void)n_in; (void)out_size;

    // bf16 weight pool (pairs contiguous for fused GEMMs)
    unsigned short* winp = wbf;            // 128x128
    unsigned short* w1l  = wbf + 16384;    // 256x128 | w1r right after -> [512,128]
    unsigned short* w1r  = w1l + 32768;
    unsigned short* w2l  = w1r + 32768;
    unsigned short* w2r  = w2l + 32768;
    unsigned short* wal  = w2r + 32768;
    unsigned short* war  = wal + 32768;
    unsigned short* wg   = war + 32768;    // 128x128 | wbe right after -> [256,128]
    unsigned short* wbe  = wg + 16384;
    unsigned short* wq1  = wbe + 16384;

    const int* src = ei;
    const int* dst = ei + E;

    CvtDescs cd;
    int ce = 0;
    auto addc = [&](const float* s, unsigned short* d, int n) { cd.src[ce] = s; cd.dst[ce] = d; cd.n4[ce] = n / 4; ++ce; };
    addc(x, xbf, N * 128);
    addc(inp_W, winp, 16384);
    addc((fp)d_in[6],  w1l, 32768); addc((fp)d_in[8],  w1r, 32768);
    addc((fp)d_in[13], w2l, 32768); addc((fp)d_in[15], w2r, 32768);
    addc((fp)d_in[20], wal, 32768); addc((fp)d_in[22], war, 32768);
    addc(g_W, wg, 16384); addc(be_W, wbe, 16384); addc(q1_W, wq1, 16384);
    cd.cnt = ce;
    cvt_many_kernel<<<2048, 256, 0, stream>>>(cd);

    hipMemsetAsync(deg, 0, (size_t)N * 4, stream);
    hist_kernel<<<(E + 255) / 256, 256, 0, stream>>>(dst, deg, E);
    scan_kernel<<<1, 1024, 0, stream>>>(deg, rowp, cur, N);
    scatter_kernel<<<(E + 255) / 256, 256, 0, stream>>>(src, dst, cur, csrs, csre, E);

    const int my = (N + 127) / 128;
    const int gatg = (N + 1) / 2;

    // h0 = relu(x @ inp_W^T + inp_b) -> bf16
    gemm_mfma_kernel<true, false, true><<<dim3(2, my), 256, 0, stream>>>(
        xbf, winp, inp_b, inp_b, 128, nullptr, hbf, N, 128, 128);

    // s1: fused xl|xr gemm -> xfb bf16; gat -> hbf
    gemm_mfma_kernel<false, false, true><<<dim3(8, my), 256, 0, stream>>>(
        hbf, w1l, (fp)d_in[7], (fp)d_in[9], 256, nullptr, xfb, N, 512, 128);
    gat_kernel<<<gatg, 256, 0, stream>>>(xfb, rowp, csrs, csre, ea,
                                         (fp)d_in[10], (fp)d_in[11], (fp)d_in[12], nullptr, hbf, N);
    // s2: gat -> h (f32, FiLM input)
    gemm_mfma_kernel<false, false, true><<<dim3(8, my), 256, 0, stream>>>(
        hbf, w2l, (fp)d_in[14], (fp)d_in[16], 256, nullptr, xfb, N, 512, 128);
    gat_kernel<<<gatg, 256, 0, stream>>>(xfb, rowp, csrs, csre, ea,
                                         (fp)d_in[17], (fp)d_in[18], (fp)d_in[19], h, nullptr, N);

    // FiLM: a = relu(action@ap^T+ap_b) -> abf; fused gamma|beta gemm -> xgb; film -> hbf
    gemm_kernel<16, true, true><<<dim3(2, (N + 63) / 64), 256, 0, stream>>>(
        action, ap_W, ap_b, abuf, abf, N, 128, 16);
    gemm_mfma_kernel<false, true, false><<<dim3(4, my), 256, 0, stream>>>(
        abf, wg, g_b, be_b, 128, xgb, nullptr, N, 256, 128);
    film_kernel<<<1024, 256, 0, stream>>>((const float4*)h, (const float4*)xgb,
                                          (ushort4*)hbf, N * 128 / 4);

    // sa
    gemm_mfma_kernel<false, false, true><<<dim3(8, my), 256, 0, stream>>>(
        hbf, wal, (fp)d_in[21], (fp)d_in[23], 256, nullptr, xfb, N, 512, 128);
    gat_kernel<<<gatg, 256, 0, stream>>>(xfb, rowp, csrs, csre, ea,
                                         (fp)d_in[24], (fp)d_in[25], (fp)d_in[26], nullptr, hbf, N);

    // q1 + scalar head via column-sum trick
    gemm_mfma_kernel<true, true, false><<<dim3(2, my), 256, 0, stream>>>(
        hbf, wq1, q1_b, q1_b, 128, xgb, nullptr, N, 128, 128);
    hipMemsetAsync(col, 0, 128 * 4, stream);
    colsum_kernel<<<256, 256, 0, stream>>>(xgb, col, N);
    final_kernel<<<1, 128, 0, stream>>>(col, q2_W, q2_b, (float*)d_out, 1.0f / (float)N);
}

// Round 5
// 764.091 us; speedup vs baseline: 1.1291x; 1.1016x over previous
//
#include <hip/hip_runtime.h>
#include <hip/hip_bf16.h>

// EdgeAwareCritic: 3x GATv2 (H=2 heads, HID=128) + FiLM + MLP head, scalar output.
// fp32 inputs; GEMMs in bf16 MFMA (fp32 accumulate). GAT is 3-phase:
//   P1 edge-parallel logits (no serial chain), P2 per-node exact softmax,
//   P3 per-node weighted gather-sum (dual accumulator chains).

typedef __attribute__((ext_vector_type(8))) short bf16x8;   // 8 bf16 = 4 VGPR
typedef __attribute__((ext_vector_type(4))) float f32x4;

__device__ __forceinline__ unsigned short f2bf(float f) {
    union { float f; unsigned int i; } v; v.f = f;
    unsigned int x = v.i;
    x += 0x7fffu + ((x >> 16) & 1u);   // round-to-nearest-even
    return (unsigned short)(x >> 16);
}
__device__ __forceinline__ float4 b4f(ushort4 u) {
    union { unsigned int i; float f; } a, b, c, d;
    a.i = (unsigned int)u.x << 16; b.i = (unsigned int)u.y << 16;
    c.i = (unsigned int)u.z << 16; d.i = (unsigned int)u.w << 16;
    return make_float4(a.f, b.f, c.f, d.f);
}

// ---------------- multi-tensor fp32 -> bf16 convert (RNE) ----------------
#define MAXCVT 12
struct CvtDescs {
    const float* src[MAXCVT];
    unsigned short* dst[MAXCVT];
    int n4[MAXCVT];
    int cnt;
};
__global__ __launch_bounds__(256) void cvt_many_kernel(CvtDescs d) {
    const int tid = blockIdx.x * blockDim.x + threadIdx.x;
    const int stride = gridDim.x * blockDim.x;
    for (int e = 0; e < d.cnt; ++e) {
        const float4* s = (const float4*)d.src[e];
        ushort4* o = (ushort4*)d.dst[e];
        const int n = d.n4[e];
        for (int i = tid; i < n; i += stride) {
            float4 v = s[i];
            o[i] = make_ushort4(f2bf(v.x), f2bf(v.y), f2bf(v.z), f2bf(v.w));
        }
    }
}

// ---------------- CSR build ----------------
__global__ void hist_kernel(const int* __restrict__ dst, int* __restrict__ deg, int n) {
    int i = blockIdx.x * blockDim.x + threadIdx.x;
    if (i < n) atomicAdd(&deg[dst[i]], 1);
}

__global__ __launch_bounds__(1024) void scan_kernel(const int* __restrict__ deg,
                                                    int* __restrict__ rowp,
                                                    int* __restrict__ cur, int n) {
    __shared__ int sums[1024];
    const int t = threadIdx.x;
    const int PER = 20;
    int base = t * PER;
    int local[PER];
    int run = 0;
#pragma unroll
    for (int i = 0; i < PER; ++i) {
        int v = (base + i < n) ? deg[base + i] : 0;
        local[i] = run; run += v;
    }
    sums[t] = run; __syncthreads();
    for (int off = 1; off < 1024; off <<= 1) {
        int v = (t >= off) ? sums[t - off] : 0;
        __syncthreads();
        sums[t] += v;
        __syncthreads();
    }
    int offs = (t > 0) ? sums[t - 1] : 0;
#pragma unroll
    for (int i = 0; i < PER; ++i) {
        int idx = base + i;
        if (idx < n) { int v = offs + local[i]; rowp[idx] = v; cur[idx] = v; }
    }
    if (t == 0) rowp[n] = sums[1023];
}

__global__ void scatter_kernel(const int* __restrict__ src, const int* __restrict__ dst,
                               int* __restrict__ cur, int* __restrict__ csrs,
                               int* __restrict__ csrd, int* __restrict__ csre, int n) {
    int i = blockIdx.x * blockDim.x + threadIdx.x;
    if (i < n) {
        int d = dst[i];
        int p = atomicAdd(&cur[d], 1);
        csrs[p] = src[i];
        csrd[p] = d;
        csre[p] = i;
    }
}

// ---------------- bf16 MFMA GEMM: C[M,N] = A[M,K]bf16 @ W[N,K]bf16^T + bias ----
template <bool RELU, bool WF32, bool WBF16>
__global__ __launch_bounds__(256) void gemm_mfma_kernel(
    const unsigned short* __restrict__ A, const unsigned short* __restrict__ W,
    const float* __restrict__ bias0, const float* __restrict__ bias1, int bsplit,
    float* __restrict__ C, unsigned short* __restrict__ Cbf, int M, int N, int K) {
    const int t = threadIdx.x;
    const int wave = t >> 6, lane = t & 63;
    const int lo = lane & 15, quad = lane >> 4;
    const int m0 = blockIdx.y * 128 + wave * 32;
    const int n0 = blockIdx.x * 64;

    f32x4 acc[2][4];
#pragma unroll
    for (int i = 0; i < 2; ++i)
#pragma unroll
        for (int j = 0; j < 4; ++j) acc[i][j] = (f32x4){0.f, 0.f, 0.f, 0.f};

    for (int k0 = 0; k0 < K; k0 += 32) {
        bf16x8 af[2], bfr[4];
#pragma unroll
        for (int mi = 0; mi < 2; ++mi) {
            const int mb = m0 + mi * 16;
            if (mb < M)
                af[mi] = *(const bf16x8*)(A + (size_t)(mb + lo) * K + k0 + quad * 8);
            else
                af[mi] = (bf16x8){0, 0, 0, 0, 0, 0, 0, 0};
        }
#pragma unroll
        for (int ni = 0; ni < 4; ++ni)
            bfr[ni] = *(const bf16x8*)(W + (size_t)(n0 + ni * 16 + lo) * K + k0 + quad * 8);
#pragma unroll
        for (int mi = 0; mi < 2; ++mi)
#pragma unroll
            for (int ni = 0; ni < 4; ++ni)
                acc[mi][ni] = __builtin_amdgcn_mfma_f32_16x16x32_bf16(af[mi], bfr[ni], acc[mi][ni], 0, 0, 0);
    }

    float bn[4];
#pragma unroll
    for (int ni = 0; ni < 4; ++ni) {
        const int n = n0 + ni * 16 + lo;
        const float* bp = (n < bsplit) ? bias0 : bias1;
        const int bi = (n < bsplit) ? n : n - bsplit;
        bn[ni] = bp[bi];
    }
#pragma unroll
    for (int mi = 0; mi < 2; ++mi) {
        const int mb = m0 + mi * 16;
        if (mb >= M) continue;
#pragma unroll
        for (int ni = 0; ni < 4; ++ni) {
            const int n = n0 + ni * 16 + lo;
#pragma unroll
            for (int r = 0; r < 4; ++r) {
                float o = acc[mi][ni][r] + bn[ni];
                if (RELU) o = fmaxf(o, 0.f);
                const size_t idx = (size_t)(mb + quad * 4 + r) * N + n;
                if (WF32) C[idx] = o;
                if (WBF16) Cbf[idx] = f2bf(o);
            }
        }
    }
}

// ---------------- fp32 vector GEMM (only for ap: K=16) ----------------
template <int BK, bool RELU, bool WBF16>
__global__ __launch_bounds__(256) void gemm_kernel(const float* __restrict__ A,
                                                   const float* __restrict__ W,
                                                   const float* __restrict__ bp,
                                                   float* __restrict__ C,
                                                   unsigned short* __restrict__ Cbf,
                                                   int M, int N, int K) {
    __shared__ float As[BK][68];
    __shared__ float Ws[BK][68];
    const int t = threadIdx.x;
    const int m0 = blockIdx.y * 64;
    const int n0 = blockIdx.x * 64;
    const int tx = t & 15, ty = t >> 4;
    float acc[4][4];
#pragma unroll
    for (int i = 0; i < 4; ++i)
#pragma unroll
        for (int j = 0; j < 4; ++j) acc[i][j] = 0.f;

    for (int k0 = 0; k0 < K; k0 += BK) {
        const int r = t >> 2, cc = (t & 3) * 4;
        const int arow = m0 + r;
        float4 av = (arow < M) ? *(const float4*)(A + (size_t)arow * K + k0 + cc)
                               : make_float4(0.f, 0.f, 0.f, 0.f);
        As[cc + 0][r] = av.x; As[cc + 1][r] = av.y;
        As[cc + 2][r] = av.z; As[cc + 3][r] = av.w;
        float4 wv = *(const float4*)(W + (size_t)(n0 + r) * K + k0 + cc);
        Ws[cc + 0][r] = wv.x; Ws[cc + 1][r] = wv.y;
        Ws[cc + 2][r] = wv.z; Ws[cc + 3][r] = wv.w;
        __syncthreads();
#pragma unroll
        for (int k = 0; k < BK; ++k) {
            float4 a4 = *(const float4*)&As[k][ty * 4];
            float4 b4 = *(const float4*)&Ws[k][tx * 4];
            float a_[4] = {a4.x, a4.y, a4.z, a4.w};
            float b_[4] = {b4.x, b4.y, b4.z, b4.w};
#pragma unroll
            for (int i = 0; i < 4; ++i)
#pragma unroll
                for (int j = 0; j < 4; ++j) acc[i][j] += a_[i] * b_[j];
        }
        __syncthreads();
    }
    float4 bj = *(const float4*)(bp + n0 + tx * 4);
    float bb[4] = {bj.x, bj.y, bj.z, bj.w};
#pragma unroll
    for (int i = 0; i < 4; ++i) {
        int row = m0 + ty * 4 + i;
        if (row < M) {
            float o[4];
#pragma unroll
            for (int j = 0; j < 4; ++j) {
                o[j] = acc[i][j] + bb[j];
                if (RELU) o[j] = fmaxf(o[j], 0.f);
            }
            *(float4*)(C + (size_t)row * N + n0 + tx * 4) = make_float4(o[0], o[1], o[2], o[3]);
            if (WBF16)
                *(ushort4*)(Cbf + (size_t)row * N + n0 + tx * 4) =
                    make_ushort4(f2bf(o[0]), f2bf(o[1]), f2bf(o[2]), f2bf(o[3]));
        }
    }
}

// ---------------- GAT P1: edge-parallel logits ----------------
// One wave per contiguous chunk of CSR positions. Per position p:
// logit[h][p] = att_h . leaky(xl[src] + xr[dst] + ea[e]@We_h^T). No carried deps.
__global__ __launch_bounds__(256) void gat_logit_kernel(
    const unsigned short* __restrict__ xfull,
    const int* __restrict__ csrs, const int* __restrict__ csrd, const int* __restrict__ csre,
    const float* __restrict__ ea, const float* __restrict__ We,
    const float* __restrict__ att, float* __restrict__ logit, int E) {
    const int lane = threadIdx.x & 63;
    const int gw = blockIdx.x * 4 + (threadIdx.x >> 6);
    const int nw = gridDim.x * 4;

    // register-cache We rows 4*lane..4*lane+3 as float2 pairs (pk-fma friendly)
    float2 wreg[4][8];
#pragma unroll
    for (int j = 0; j < 4; ++j) {
        const float4* wp = (const float4*)(We + (size_t)(4 * lane + j) * 16);
#pragma unroll
        for (int q = 0; q < 4; ++q) {
            float4 u = wp[q];
            wreg[j][q * 2 + 0] = make_float2(u.x, u.y);
            wreg[j][q * 2 + 1] = make_float2(u.z, u.w);
        }
    }
    const float4 att4 = *(const float4*)(att + 4 * lane);

    const int chunk = (E + nw - 1) / nw;
    const int p0 = gw * chunk;
    const int p1 = min(E, p0 + chunk);
    for (int p = p0; p < p1; ++p) {
        const int s = csrs[p], d = csrd[p], e = csre[p];
        const float4 xl4 = b4f(*(const ushort4*)(xfull + (size_t)s * 512 + 4 * lane));
        const float4 xr4 = b4f(*(const ushort4*)(xfull + (size_t)d * 512 + 256 + 4 * lane));
        const float4* ep = (const float4*)(ea + (size_t)e * 16);
        float2 ev[8];
#pragma unroll
        for (int q = 0; q < 4; ++q) {
            float4 u = ep[q];
            ev[q * 2 + 0] = make_float2(u.x, u.y);
            ev[q * 2 + 1] = make_float2(u.z, u.w);
        }
        float2 a0 = make_float2(0.f, 0.f), a1 = a0, a2 = a0, a3 = a0;
#pragma unroll
        for (int k = 0; k < 8; ++k) {
            a0.x += ev[k].x * wreg[0][k].x; a0.y += ev[k].y * wreg[0][k].y;
            a1.x += ev[k].x * wreg[1][k].x; a1.y += ev[k].y * wreg[1][k].y;
            a2.x += ev[k].x * wreg[2][k].x; a2.y += ev[k].y * wreg[2][k].y;
            a3.x += ev[k].x * wreg[3][k].x; a3.y += ev[k].y * wreg[3][k].y;
        }
        float sx = xl4.x + xr4.x + a0.x + a0.y;
        float sy = xl4.y + xr4.y + a1.x + a1.y;
        float sz = xl4.z + xr4.z + a2.x + a2.y;
        float sw = xl4.w + xr4.w + a3.x + a3.y;
        sx = fmaxf(sx, 0.2f * sx); sy = fmaxf(sy, 0.2f * sy);
        sz = fmaxf(sz, 0.2f * sz); sw = fmaxf(sw, 0.2f * sw);
        float tv = sx * att4.x + sy * att4.y + sz * att4.z + sw * att4.w;
        tv += __shfl_xor(tv, 1);  tv += __shfl_xor(tv, 2);  tv += __shfl_xor(tv, 4);
        tv += __shfl_xor(tv, 8);  tv += __shfl_xor(tv, 16);
        if ((lane & 31) == 0) logit[(size_t)(lane >> 5) * E + p] = tv;
    }
}

// ---------------- GAT P2: per-node exact segment softmax ----------------
// Wave per node; lanes 0-31 head0 edges, 32-63 head1. Overwrites logit with
// w = exp(l - max); writes den[node*2+h].
__global__ __launch_bounds__(256) void gat_norm_kernel(
    const int* __restrict__ rowp, float* __restrict__ logit,
    float* __restrict__ den, int nnodes, int E) {
    const int lane = threadIdx.x & 63;
    const int node = blockIdx.x * 4 + (threadIdx.x >> 6);
    if (node >= nnodes) return;
    const int rs = rowp[node], re = rowp[node + 1];
    const int h = lane >> 5, l = lane & 31;
    float* lg = logit + (size_t)h * E;
    float mx = -INFINITY;
    for (int base = rs; base < re; base += 32) {
        const int idx = base + l;
        if (idx < re) mx = fmaxf(mx, lg[idx]);
    }
    mx = fmaxf(mx, __shfl_xor(mx, 1));  mx = fmaxf(mx, __shfl_xor(mx, 2));
    mx = fmaxf(mx, __shfl_xor(mx, 4));  mx = fmaxf(mx, __shfl_xor(mx, 8));
    mx = fmaxf(mx, __shfl_xor(mx, 16));
    float sum = 0.f;
    for (int base = rs; base < re; base += 32) {
        const int idx = base + l;
        if (idx < re) {
            float p = __expf(lg[idx] - mx);
            lg[idx] = p;
            sum += p;
        }
    }
    sum += __shfl_xor(sum, 1);  sum += __shfl_xor(sum, 2);  sum += __shfl_xor(sum, 4);
    sum += __shfl_xor(sum, 8);  sum += __shfl_xor(sum, 16);
    if (l == 0) den[node * 2 + h] = sum;
}

// ---------------- GAT P3: per-node weighted gather-sum ----------------
// Wave per node; lane owns 4 channels of one head (offset 4*lane into xl cols).
// out = relu(mean_heads(sum_e w*xl[src]/den) + bias) -> f32 and/or bf16.
__global__ __launch_bounds__(256) void gat_aggr_kernel(
    const unsigned short* __restrict__ xfull,
    const int* __restrict__ rowp, const int* __restrict__ csrs,
    const float* __restrict__ wgt, const float* __restrict__ den,
    const float* __restrict__ bias,
    float* __restrict__ houtf, unsigned short* __restrict__ houtb, int nnodes, int E) {
    const int lane = threadIdx.x & 63;
    const int node = blockIdx.x * 4 + (threadIdx.x >> 6);
    if (node >= nnodes) return;
    const int rs = rowp[node], re = rowp[node + 1];
    const int h = lane >> 5;
    const float* wp = wgt + (size_t)h * E;
    float4 acc0 = make_float4(0.f, 0.f, 0.f, 0.f), acc1 = acc0;
    int i = rs;
    for (; i + 1 < re; i += 2) {
        const int s0 = csrs[i], s1 = csrs[i + 1];
        const float w0 = wp[i], w1 = wp[i + 1];
        const float4 x0 = b4f(*(const ushort4*)(xfull + (size_t)s0 * 512 + 4 * lane));
        const float4 x1 = b4f(*(const ushort4*)(xfull + (size_t)s1 * 512 + 4 * lane));
        acc0.x += w0 * x0.x; acc0.y += w0 * x0.y; acc0.z += w0 * x0.z; acc0.w += w0 * x0.w;
        acc1.x += w1 * x1.x; acc1.y += w1 * x1.y; acc1.z += w1 * x1.z; acc1.w += w1 * x1.w;
    }
    if (i < re) {
        const int s0 = csrs[i];
        const float w0 = wp[i];
        const float4 x0 = b4f(*(const ushort4*)(xfull + (size_t)s0 * 512 + 4 * lane));
        acc0.x += w0 * x0.x; acc0.y += w0 * x0.y; acc0.z += w0 * x0.z; acc0.w += w0 * x0.w;
    }
    float ox = acc0.x + acc1.x, oy = acc0.y + acc1.y;
    float oz = acc0.z + acc1.z, ow = acc0.w + acc1.w;
    const float dn = den[node * 2 + h];
    const float inv = (re > rs) ? 1.f / dn : 0.f;
    ox *= inv; oy *= inv; oz *= inv; ow *= inv;
    ox += __shfl_xor(ox, 32); oy += __shfl_xor(oy, 32);
    oz += __shfl_xor(oz, 32); ow += __shfl_xor(ow, 32);
    if (lane < 32) {
        float4 bu = *(const float4*)(bias + 4 * lane);
        float4 o;
        o.x = fmaxf(0.5f * ox + bu.x, 0.f);
        o.y = fmaxf(0.5f * oy + bu.y, 0.f);
        o.z = fmaxf(0.5f * oz + bu.z, 0.f);
        o.w = fmaxf(0.5f * ow + bu.w, 0.f);
        if (houtf) *(float4*)(houtf + (size_t)node * 128 + 4 * lane) = o;
        if (houtb) *(ushort4*)(houtb + (size_t)node * 128 + 4 * lane) =
            make_ushort4(f2bf(o.x), f2bf(o.y), f2bf(o.z), f2bf(o.w));
    }
}

// ---------------- FiLM: hbf = bf16(gm*h + bm); gm|bm fused in xgb [N,256] ----
__global__ void film_kernel(const float4* __restrict__ h, const float4* __restrict__ xgb,
                            ushort4* __restrict__ hbf, int n4) {
    for (int i = blockIdx.x * blockDim.x + threadIdx.x; i < n4; i += gridDim.x * blockDim.x) {
        const int row = i >> 5, c4 = i & 31;
        float4 hv = h[i];
        float4 g = xgb[row * 64 + c4];
        float4 b = xgb[row * 64 + 32 + c4];
        float ox = g.x * hv.x + b.x, oy = g.y * hv.y + b.y;
        float oz = g.z * hv.z + b.z, ow = g.w * hv.w + b.w;
        hbf[i] = make_ushort4(f2bf(ox), f2bf(oy), f2bf(oz), f2bf(ow));
    }
}

// ---------------- column sum of h[rows,128] -> col[128] ----------------
__global__ __launch_bounds__(256) void colsum_kernel(const float* __restrict__ h,
                                                     float* __restrict__ col, int rows) {
    int c = threadIdx.x & 127;
    int r = blockIdx.x * 2 + (threadIdx.x >> 7);
    float s = 0.f;
    for (; r < rows; r += gridDim.x * 2) s += h[(size_t)r * 128 + c];
    atomicAdd(&col[c], s);
}

// ---------------- out = dot(col/N, q2_W) + q2_b ----------------
__global__ __launch_bounds__(128) void final_kernel(const float* __restrict__ col,
                                                    const float* __restrict__ q2w,
                                                    const float* __restrict__ q2b,
                                                    float* __restrict__ out, float invn) {
    __shared__ float red[128];
    int t = threadIdx.x;
    red[t] = col[t] * invn * q2w[t];
    __syncthreads();
    for (int off = 64; off > 0; off >>= 1) {
        if (t < off) red[t] += red[t + off];
        __syncthreads();
    }
    if (t == 0) out[0] = red[0] + q2b[0];
}

extern "C" void kernel_launch(void* const* d_in, const int* in_sizes, int n_in,
                              void* d_out, int out_size, void* d_ws, size_t ws_size,
                              hipStream_t stream) {
    const int N = in_sizes[0] / 128;   // 20000
    const int E = in_sizes[1] / 2;     // 320000

    typedef const float* fp;
    fp x      = (fp)d_in[0];
    const int* ei = (const int*)d_in[1];
    fp ea     = (fp)d_in[2];
    fp action = (fp)d_in[3];
    fp inp_W  = (fp)d_in[4];
    fp inp_b  = (fp)d_in[5];
    fp ap_W = (fp)d_in[27], ap_b = (fp)d_in[28];
    fp g_W  = (fp)d_in[29], g_b  = (fp)d_in[30];
    fp be_W = (fp)d_in[31], be_b = (fp)d_in[32];
    fp q1_W = (fp)d_in[33], q1_b = (fp)d_in[34];
    fp q2_W = (fp)d_in[35], q2_b = (fp)d_in[36];

    char* base = (char*)d_ws;
    size_t off = 0;
    auto alloc = [&](size_t bytes) { char* p = base + off; off = (off + bytes + 255) & ~(size_t)255; return p; };
    float* h    = (float*)alloc((size_t)N * 128 * 4);             // f32 gat out (film input)
    unsigned short* xfb = (unsigned short*)alloc((size_t)N * 512 * 2);  // fused xl|xr bf16
    float* xgb  = (float*)alloc((size_t)N * 256 * 4);             // fused gamma|beta f32 / q1 out
    float* col  = (float*)alloc(128 * 4);
    int* deg    = (int*)alloc((size_t)N * 4);
    int* rowp   = (int*)alloc((size_t)(N + 1) * 4);
    int* cur    = (int*)alloc((size_t)N * 4);
    int* csrs   = (int*)alloc((size_t)E * 4);
    int* csrd   = (int*)alloc((size_t)E * 4);
    int* csre   = (int*)alloc((size_t)E * 4);
    float* wgt  = (float*)alloc((size_t)2 * E * 4);               // logits -> softmax weights
    float* den  = (float*)alloc((size_t)N * 2 * 4);
    unsigned short* hbf = (unsigned short*)alloc((size_t)N * 128 * 2);
    unsigned short* xbf = (unsigned short*)alloc((size_t)N * 128 * 2);  // x bf16, later a bf16
    unsigned short* wbf = (unsigned short*)alloc(262144 * 2);
    float* abuf = (float*)xfb;             // ap f32 out: xfb region dead at FiLM stage
    unsigned short* abf = xbf;             // x_bf dead after inp gemm
    (void)ws_size; (void)n_in; (void)out_size;

    unsigned short* winp = wbf;            // 128x128
    unsigned short* w1l  = wbf + 16384;    // 256x128 | w1r contiguous -> [512,128]
    unsigned short* w1r  = w1l + 32768;
    unsigned short* w2l  = w1r + 32768;
    unsigned short* w2r  = w2l + 32768;
    unsigned short* wal  = w2r + 32768;
    unsigned short* war  = wal + 32768;
    unsigned short* wg   = war + 32768;    // 128x128 | wbe contiguous -> [256,128]
    unsigned short* wbe  = wg + 16384;
    unsigned short* wq1  = wbe + 16384;

    const int* src = ei;
    const int* dst = ei + E;

    CvtDescs cd;
    int ce = 0;
    auto addc = [&](const float* s, unsigned short* d, int n) { cd.src[ce] = s; cd.dst[ce] = d; cd.n4[ce] = n / 4; ++ce; };
    addc(x, xbf, N * 128);
    addc(inp_W, winp, 16384);
    addc((fp)d_in[6],  w1l, 32768); addc((fp)d_in[8],  w1r, 32768);
    addc((fp)d_in[13], w2l, 32768); addc((fp)d_in[15], w2r, 32768);
    addc((fp)d_in[20], wal, 32768); addc((fp)d_in[22], war, 32768);
    addc(g_W, wg, 16384); addc(be_W, wbe, 16384); addc(q1_W, wq1, 16384);
    cd.cnt = ce;
    cvt_many_kernel<<<2048, 256, 0, stream>>>(cd);

    hipMemsetAsync(deg, 0, (size_t)N * 4, stream);
    hist_kernel<<<(E + 255) / 256, 256, 0, stream>>>(dst, deg, E);
    scan_kernel<<<1, 1024, 0, stream>>>(deg, rowp, cur, N);
    scatter_kernel<<<(E + 255) / 256, 256, 0, stream>>>(src, dst, cur, csrs, csrd, csre, E);

    const int my = (N + 127) / 128;
    const int nodeg = (N + 3) / 4;

    auto run_gat = [&](const float* We, const float* at, const float* bi,
                       float* hf, unsigned short* hb) {
        gat_logit_kernel<<<2048, 256, 0, stream>>>(xfb, csrs, csrd, csre, ea, We, at, wgt, E);
        gat_norm_kernel<<<nodeg, 256, 0, stream>>>(rowp, wgt, den, N, E);
        gat_aggr_kernel<<<nodeg, 256, 0, stream>>>(xfb, rowp, csrs, wgt, den, bi, hf, hb, N, E);
    };

    // h0 = relu(x @ inp_W^T + inp_b) -> bf16
    gemm_mfma_kernel<true, false, true><<<dim3(2, my), 256, 0, stream>>>(
        xbf, winp, inp_b, inp_b, 128, nullptr, hbf, N, 128, 128);

    // s1
    gemm_mfma_kernel<false, false, true><<<dim3(8, my), 256, 0, stream>>>(
        hbf, w1l, (fp)d_in[7], (fp)d_in[9], 256, nullptr, xfb, N, 512, 128);
    run_gat((fp)d_in[10], (fp)d_in[11], (fp)d_in[12], nullptr, hbf);
    // s2 (gat writes h f32 for FiLM)
    gemm_mfma_kernel<false, false, true><<<dim3(8, my), 256, 0, stream>>>(
        hbf, w2l, (fp)d_in[14], (fp)d_in[16], 256, nullptr, xfb, N, 512, 128);
    run_gat((fp)d_in[17], (fp)d_in[18], (fp)d_in[19], h, nullptr);

    // FiLM: a = relu(action@ap^T+ap_b) -> abf; fused gamma|beta gemm -> xgb; film -> hbf
    gemm_kernel<16, true, true><<<dim3(2, (N + 63) / 64), 256, 0, stream>>>(
        action, ap_W, ap_b, abuf, abf, N, 128, 16);
    gemm_mfma_kernel<false, true, false><<<dim3(4, my), 256, 0, stream>>>(
        abf, wg, g_b, be_b, 128, xgb, nullptr, N, 256, 128);
    film_kernel<<<1024, 256, 0, stream>>>((const float4*)h, (const float4*)xgb,
                                          (ushort4*)hbf, N * 128 / 4);

    // sa
    gemm_mfma_kernel<false, false, true><<<dim3(8, my), 256, 0, stream>>>(
        hbf, wal, (fp)d_in[21], (fp)d_in[23], 256, nullptr, xfb, N, 512, 128);
    run_gat((fp)d_in[24], (fp)d_in[25], (fp)d_in[26], nullptr, hbf);

    // q1 + scalar head via column-sum trick
    gemm_mfma_kernel<true, true, false><<<dim3(2, my), 256, 0, stream>>>(
        hbf, wq1, q1_b, q1_b, 128, xgb, nullptr, N, 128, 128);
    hipMemsetAsync(col, 0, 128 * 4, stream);
    colsum_kernel<<<256, 256, 0, stream>>>(xgb, col, N);
    final_kernel<<<1, 128, 0, stream>>>(col, q2_W, q2_b, (float*)d_out, 1.0f / (float)N);
}